// Round 1
// baseline (1087.849 us; speedup 1.0000x reference)
//
#include <hip/hip_runtime.h>

// PlasticLSTM: T=256, B=32, I=128, H=256, 4H=1024, CLIP=2
// d_out: hs[T,B,H] ++ h[B,H] ++ c[B,H] ++ hebb[B,H,H]  (fp32, concat flat)
//
// Round-11: 2-way split-K (64 blocks = 2 roles x 32 batch, 1024 thr).
// Each role block holds HALF of Wh in registers (16 uint4 = 128 f16/thread)
// and half the hebb rows (16 h2/thread); alpha lives in LDS (64 KiB).
// Exchange: ONE partner, same proven tagged {tag=t+1 | f32} ping-pong
// protocol. Plast partials (pp) are published immediately after phase 1a
// (consumer-side fold), so the pp round trip hides under the matvec and
// B1 is off the publish path. xf for step t+1 is prefetched at step t.

#define TT 256
#define BB 32
#define II 128
#define HH 256
#define G4 1024

typedef _Float16 h2_t __attribute__((ext_vector_type(2)));
typedef unsigned long long u64;

__device__ __forceinline__ float sigm(float x) {
    return 1.0f / (1.0f + __expf(-x));
}
__device__ __forceinline__ float tanhfast(float x) {
    return 1.0f - 2.0f / (__expf(2.0f * x) + 1.0f);
}
__device__ __forceinline__ unsigned pkh(float lo, float hi) {
    h2_t v;
    v.x = (_Float16)lo;
    v.y = (_Float16)hi;
    return __builtin_bit_cast(unsigned, v);
}

#if __has_builtin(__builtin_amdgcn_fdot2)
__device__ __forceinline__ float dot2(unsigned a, unsigned b, float c) {
    return __builtin_amdgcn_fdot2(__builtin_bit_cast(h2_t, a),
                                  __builtin_bit_cast(h2_t, b), c, false);
}
#else
__device__ __forceinline__ float dot2(unsigned a, unsigned b, float c) {
    h2_t av = __builtin_bit_cast(h2_t, a), bv = __builtin_bit_cast(h2_t, b);
    return c + (float)av.x * (float)bv.x + (float)av.y * (float)bv.y;
}
#endif

__device__ __forceinline__ h2_t pkfma(h2_t a, h2_t b, h2_t c) {
#if __has_builtin(__builtin_elementwise_fma)
    return __builtin_elementwise_fma(a, b, c);
#else
    return a * b + c;
#endif
}
__device__ __forceinline__ h2_t clip2h(h2_t x) {
    const h2_t lo = {(_Float16)-2.0f, (_Float16)-2.0f};
    const h2_t hi = {(_Float16)2.0f, (_Float16)2.0f};
#if __has_builtin(__builtin_elementwise_max) && __has_builtin(__builtin_elementwise_min)
    return __builtin_elementwise_min(__builtin_elementwise_max(x, lo), hi);
#else
    h2_t r = x;
    r.x = r.x < lo.x ? lo.x : (r.x > hi.x ? hi.x : r.x);
    r.y = r.y < lo.y ? lo.y : (r.y > hi.y ? hi.y : r.y);
    return r;
#endif
}

// ---------------------------------------------------------------------------
// Wd2: idx = Q*1024 + g (Q=0..31); entry = 8 f16 of Wh[g][8Q .. 8Q+7]
// Role r's thread g uses Q = r*16 .. r*16+15.
// ---------------------------------------------------------------------------
__global__ __launch_bounds__(256) void prep_wd2(const float* __restrict__ Wh,
                                                uint4* __restrict__ Wd2) {
    int idx = blockIdx.x * 256 + threadIdx.x;   // 32768
    int Q = idx >> 10, g = idx & 1023;
    const float4* s = (const float4*)(Wh + (size_t)g * HH + (Q << 3));
    float4 a = s[0], b2 = s[1];
    uint4 o;
    o.x = pkh(a.x, a.y);
    o.y = pkh(a.z, a.w);
    o.z = pkh(b2.x, b2.y);
    o.w = pkh(b2.z, b2.w);
    Wd2[idx] = o;
}

// ---------------------------------------------------------------------------
// alP: per-role LDS image. idx = r*16384 + (pg*256 + k)*2 + j
// pair p = 2*pg + j ; value = {alpha[r*128 + 2p][k], alpha[r*128 + 2p+1][k]}
// ---------------------------------------------------------------------------
__global__ __launch_bounds__(256) void prep_alp(const float* __restrict__ alpha,
                                                unsigned* __restrict__ alP) {
    int idx = blockIdx.x * 256 + threadIdx.x;   // 32768
    int r = idx >> 14, rem = idx & 16383;
    int j = rem & 1, kk = (rem >> 1) & 255, pg = rem >> 9;
    int row0 = r * 128 + 4 * pg + 2 * j;
    float a0 = alpha[(size_t)row0 * HH + kk];
    float a1 = alpha[(size_t)(row0 + 1) * HH + kk];
    alP[idx] = pkh(a0, a1);
}

// ---------------------------------------------------------------------------
// xf[t,b,g] = sum_i x[t,b,i]*Wx[g,i] + bx[g] + bh[g]
// ---------------------------------------------------------------------------
__global__ __launch_bounds__(256) void xf_gemm(const float* __restrict__ x,
                                               const float* __restrict__ Wx,
                                               const float* __restrict__ bx,
                                               const float* __restrict__ bh,
                                               float* __restrict__ xf) {
    __shared__ float As[64][37];
    __shared__ float Bs[64][37];
    const int tid = threadIdx.x;
    const int tx = tid & 15, ty = tid >> 4;
    const int m0 = blockIdx.y << 6;
    const int n0 = blockIdx.x << 6;
    float c[4][4] = {};

    for (int k0 = 0; k0 < II; k0 += 32) {
#pragma unroll
        for (int hh = 0; hh < 2; ++hh) {
            int row = (tid >> 3) + (hh << 5);
            int col = (tid & 7) << 2;
            float4 va = *(const float4*)(x + (size_t)(m0 + row) * II + k0 + col);
            As[row][col] = va.x; As[row][col + 1] = va.y;
            As[row][col + 2] = va.z; As[row][col + 3] = va.w;
            float4 vb = *(const float4*)(Wx + (size_t)(n0 + row) * II + k0 + col);
            Bs[row][col] = vb.x; Bs[row][col + 1] = vb.y;
            Bs[row][col + 2] = vb.z; Bs[row][col + 3] = vb.w;
        }
        __syncthreads();
#pragma unroll
        for (int kk = 0; kk < 32; ++kk) {
            float a[4], bb[4];
#pragma unroll
            for (int u = 0; u < 4; ++u) a[u] = As[(ty << 2) + u][kk];
#pragma unroll
            for (int v = 0; v < 4; ++v) bb[v] = Bs[(tx << 2) + v][kk];
#pragma unroll
            for (int u = 0; u < 4; ++u)
#pragma unroll
                for (int v = 0; v < 4; ++v)
                    c[u][v] = fmaf(a[u], bb[v], c[u][v]);
        }
        __syncthreads();
    }
    const int n = n0 + (tx << 2);
    float4 bxv = *(const float4*)(bx + n);
    float4 bhv = *(const float4*)(bh + n);
    float4 badd = {bxv.x + bhv.x, bxv.y + bhv.y, bxv.z + bhv.z, bxv.w + bhv.w};
#pragma unroll
    for (int u = 0; u < 4; ++u) {
        int m = m0 + (ty << 2) + u;
        float4 o = {c[u][0] + badd.x, c[u][1] + badd.y,
                    c[u][2] + badd.z, c[u][3] + badd.w};
        *(float4*)(xf + (size_t)m * G4 + n) = o;
    }
}

// ---------------------------------------------------------------------------
// hebb: 16 NAMED half2 regs/thread (rows r0g+2i, r0g+2i+1; r0g = r*128+rg*32)
// ---------------------------------------------------------------------------
#define HBQ_FOREACH(X) X(0) X(1) X(2) X(3) X(4) X(5) X(6) X(7) \
                       X(8) X(9) X(10) X(11) X(12) X(13) X(14) X(15)

#define HBQ_DECL(i) h2_t hp##i = {(_Float16)0.0f, (_Float16)0.0f};
#define HBQ_OUT(i) \
    hbout[(size_t)(r0g + 2 * i) * HH + k]     = (float)hp##i.x; \
    hbout[(size_t)(r0g + 2 * i + 1) * HH + k] = (float)hp##i.y;

#define HBQ_STEP(i, au, hou, hnu) { \
    h2_t al2 = __builtin_bit_cast(h2_t, au); \
    h2_t ho2 = __builtin_bit_cast(h2_t, hou); \
    h2_t hn2 = __builtin_bit_cast(h2_t, hnu); \
    hp##i = clip2h(pkfma(mj2, ho2, hp##i)); \
    h2_t hna = hn2 * al2; \
    pp = dot2(__builtin_bit_cast(unsigned, hna), \
              __builtin_bit_cast(unsigned, hp##i), pp); }

#define HBQ_CHUNK(q, i0, i1, i2, i3) { \
    uint4 ho = hfO4[hb4 + (q)]; \
    uint4 hn = hfN4[hb4 + (q)]; \
    uint2 A0 = *(const uint2*)&als[((((rg << 3) + 2 * (q)) << 8) + k) << 1]; \
    uint2 A1 = *(const uint2*)&als[((((rg << 3) + 2 * (q) + 1) << 8) + k) << 1]; \
    HBQ_STEP(i0, A0.x, ho.x, hn.x) \
    HBQ_STEP(i1, A0.y, ho.y, hn.y) \
    HBQ_STEP(i2, A1.x, ho.z, hn.z) \
    HBQ_STEP(i3, A1.y, ho.w, hn.w) }

#define HBV_STEP(i, hou) { \
    h2_t ho2 = __builtin_bit_cast(h2_t, hou); \
    hp##i = clip2h(pkfma(mj2, ho2, hp##i)); }
#define HBV_CHUNK(q, i0, i1, i2, i3) { \
    uint4 ho = hfO4[hb4 + (q)]; \
    HBV_STEP(i0, ho.x) HBV_STEP(i1, ho.y) \
    HBV_STEP(i2, ho.z) HBV_STEP(i3, ho.w) }

#define DOTW(W, HV) { \
    ac0 = dot2(W.x, HV.x, ac0); ac1 = dot2(W.y, HV.y, ac1); \
    ac2 = dot2(W.z, HV.z, ac2); ac3 = dot2(W.w, HV.w, ac3); }

__global__ __launch_bounds__(1024, 1) void scan_kernel(
    const float* __restrict__ xf,      // [T,B,4H], biases folded
    const uint4* __restrict__ Wd2,
    const unsigned* __restrict__ alP,
    const float* __restrict__ w_mod,
    const float* __restrict__ b_mod,
    const float* __restrict__ w_fan,
    const float* __restrict__ b_fan,
    u64* __restrict__ exData,          // [32][2][2][2048] u64 {tag|f32}
    float* __restrict__ out) {
    const int bid = blockIdx.x;
    const int r   = bid >> 5;          // role 0..1: K-half r*128..r*128+127
    const int b   = bid & 31;          // batch element
    const int tid = threadIdx.x;
    const int k   = tid & (HH - 1);
    const int rg  = tid >> 8;          // 0..3
    const int r0g = (r << 7) + (rg << 5);  // first hebb row owned
    const int hb4 = (r << 4) + (rg << 2);  // uint4 index of row r0g in hf_s

    __shared__ alignas(16) unsigned short hf_s[2][HH];
    __shared__ alignas(16) float fioj_s[G4];
    __shared__ float pp_s[4][HH];
    __shared__ float red_s[4];
    __shared__ alignas(16) unsigned als[16384];   // 64 KiB alpha (this role)

    HBQ_FOREACH(HBQ_DECL)

    // ---- stage alpha into LDS (one-time) ---------------------------------
    {
        const uint4* s4 = (const uint4*)(alP + ((size_t)r << 14));
        uint4* d4 = (uint4*)als;
        d4[tid]        = s4[tid];
        d4[tid + 1024] = s4[tid + 1024];
        d4[tid + 2048] = s4[tid + 2048];
        d4[tid + 3072] = s4[tid + 3072];
    }
    if (tid < HH) {
        hf_s[0][tid] = 0;
        hf_s[1][tid] = 0;
    }
    if (tid < 4) red_s[tid] = 0.0f;
    __syncthreads();

    const float bmod = b_mod[0];
    const float wf = w_fan[k], bf = b_fan[k], wm = w_mod[k];
    float creg = 0.0f, jreg = 0.0f, hnreg = 0.0f;

    // ---- Register-resident weights: K-half r for gate g=tid (128 f16) ----
    const uint4* wb = Wd2 + ((size_t)r << 14) + tid;
    uint4 w0 = wb[0],      w1 = wb[1024],  w2 = wb[2048],  w3 = wb[3072];
    uint4 w4 = wb[4096],   w5 = wb[5120],  w6 = wb[6144],  w7 = wb[7168];
    uint4 w8 = wb[8192],   w9 = wb[9216],  w10 = wb[10240], w11 = wb[11264];
    uint4 w12 = wb[12288], w13 = wb[13312], w14 = wb[14336], w15 = wb[15360];

    // xf: role r adds xf for gates [512r, 512r+512); prefetched 1 step ahead
    const bool hasxf = ((tid >> 9) == r);
    const float* xfp = xf + (size_t)b * G4 + tid;
    float xcur = hasxf ? xfp[0] : 0.0f;

    u64* myEx = exData + ((size_t)(b * 2 + r) << 12);
    const u64* pEx = exData + ((size_t)(b * 2 + (r ^ 1)) << 12);

    for (int t = 0; t < TT; ++t) {
        // prefetch next step's xf (latency hidden under this whole step)
        float xnext = 0.0f;
        if (hasxf && t + 1 < TT) xnext = xfp[(size_t)(t + 1) * BB * G4];

        const unsigned tag = (unsigned)(t + 1);
        const int off = (t & 1) * 2048;

        // ---- Phase 1a: eta_{t-1}; deferred hebb update + plast(t) fused ---
        float eta = tanhfast(((red_s[0] + red_s[1]) + (red_s[2] + red_s[3])) + bmod);
        float mj = fmaf(eta, wf, bf) * jreg;    // 0 at t=0
        h2_t mj2;
        mj2.x = (_Float16)mj;
        mj2.y = mj2.x;
        const uint4* hfO4 = (const uint4*)hf_s[t & 1];        // h_{t-2}
        const uint4* hfN4 = (const uint4*)hf_s[(t & 1) ^ 1];  // h_{t-1}
        float pp = 0.0f;
        HBQ_CHUNK(0, 0, 1, 2, 3)
        HBQ_CHUNK(1, 4, 5, 6, 7)
        HBQ_CHUNK(2, 8, 9, 10, 11)
        HBQ_CHUNK(3, 12, 13, 14, 15)
        pp_s[rg][k] = pp;
        // publish pp NOW — its round trip hides under the matvec below
        __hip_atomic_store(&myEx[off + 1024 + tid],
                           ((u64)tag << 32) |
                               (u64)__builtin_bit_cast(unsigned, pp),
                           __ATOMIC_RELAXED, __HIP_MEMORY_SCOPE_AGENT);

        // ---- Phase 1b: half-K gate matvec, weights in registers -----------
        float ac0 = 0.f, ac1 = 0.f, ac2 = 0.f, ac3 = 0.f;
        {
            const uint4* hv = hfN4 + (r << 4);
            uint4 hA = hv[0], hB = hv[1];
            DOTW(w0, hA) DOTW(w1, hB)
            hA = hv[2]; hB = hv[3];
            DOTW(w2, hA) DOTW(w3, hB)
            hA = hv[4]; hB = hv[5];
            DOTW(w4, hA) DOTW(w5, hB)
            hA = hv[6]; hB = hv[7];
            DOTW(w6, hA) DOTW(w7, hB)
            hA = hv[8]; hB = hv[9];
            DOTW(w8, hA) DOTW(w9, hB)
            hA = hv[10]; hB = hv[11];
            DOTW(w10, hA) DOTW(w11, hB)
            hA = hv[12]; hB = hv[13];
            DOTW(w12, hA) DOTW(w13, hB)
            hA = hv[14]; hB = hv[15];
            DOTW(w14, hA) DOTW(w15, hB)
        }
        float part = ((ac0 + ac1) + (ac2 + ac3)) + xcur;
        xcur = xnext;

        // ---- publish tagged {t+1 | part}: the store IS the signal ---------
        __hip_atomic_store(&myEx[off + tid],
                           ((u64)tag << 32) |
                               (u64)__builtin_bit_cast(unsigned, part),
                           __ATOMIC_RELAXED, __HIP_MEMORY_SCOPE_AGENT);
        __syncthreads();                                   // B1 (pp_s ready)

        // ---- poll the single partner (j-waves also fold plast) ------------
        float fv;
        if (tid < 768) {
            u64 v;
            for (;;) {
                v = __hip_atomic_load(&pEx[off + tid], __ATOMIC_RELAXED,
                                      __HIP_MEMORY_SCOPE_AGENT);
                if ((unsigned)(v >> 32) == tag) break;
            }
            fv = part + __builtin_bit_cast(float, (unsigned)v);
        } else {
            float own = (pp_s[0][k] + pp_s[1][k]) + (pp_s[2][k] + pp_s[3][k]);
            float s0 = 0.f, s1 = 0.f, s2 = 0.f, s3 = 0.f, s4 = 0.f;
            bool d0 = false, d1 = false, d2 = false, d3 = false, d4 = false;
            do {
                if (!d0) {
                    u64 v = __hip_atomic_load(&pEx[off + tid], __ATOMIC_RELAXED,
                                              __HIP_MEMORY_SCOPE_AGENT);
                    if ((unsigned)(v >> 32) == tag) {
                        s0 = __builtin_bit_cast(float, (unsigned)v);
                        d0 = true;
                    }
                }
                if (!d1) {
                    u64 v = __hip_atomic_load(&pEx[off + 1024 + k],
                                              __ATOMIC_RELAXED,
                                              __HIP_MEMORY_SCOPE_AGENT);
                    if ((unsigned)(v >> 32) == tag) {
                        s1 = __builtin_bit_cast(float, (unsigned)v);
                        d1 = true;
                    }
                }
                if (!d2) {
                    u64 v = __hip_atomic_load(&pEx[off + 1280 + k],
                                              __ATOMIC_RELAXED,
                                              __HIP_MEMORY_SCOPE_AGENT);
                    if ((unsigned)(v >> 32) == tag) {
                        s2 = __builtin_bit_cast(float, (unsigned)v);
                        d2 = true;
                    }
                }
                if (!d3) {
                    u64 v = __hip_atomic_load(&pEx[off + 1536 + k],
                                              __ATOMIC_RELAXED,
                                              __HIP_MEMORY_SCOPE_AGENT);
                    if ((unsigned)(v >> 32) == tag) {
                        s3 = __builtin_bit_cast(float, (unsigned)v);
                        d3 = true;
                    }
                }
                if (!d4) {
                    u64 v = __hip_atomic_load(&pEx[off + 1792 + k],
                                              __ATOMIC_RELAXED,
                                              __HIP_MEMORY_SCOPE_AGENT);
                    if ((unsigned)(v >> 32) == tag) {
                        s4 = __builtin_bit_cast(float, (unsigned)v);
                        d4 = true;
                    }
                }
            } while (!(d0 && d1 && d2 && d3 && d4));
            fv = (part + own) + (((s0 + s1) + (s2 + s3)) + s4);
        }
        fioj_s[tid] = fv;
        __syncthreads();                                   // B2 (fioj ready)

        // ---- Phase 2: cell update (redundant across roles & rg) -----------
        float fg = sigm(fioj_s[k]);
        float ig = sigm(fioj_s[HH + k]);
        float og = sigm(fioj_s[2 * HH + k]);
        float jp = fioj_s[3 * HH + k];     // plast already folded in
        jreg = tanhfast(jp);
        creg = fmaf(fg, creg, ig * jreg);
        hnreg = og * tanhfast(creg);
        if (rg == 0) {   // waves 0-3, wave-uniform
            _Float16 hh = (_Float16)hnreg;
            hf_s[t & 1][k] = __builtin_bit_cast(unsigned short, hh);
            if (r == 0) out[((size_t)t * BB + b) * HH + k] = hnreg;
            float e = creg * wm;
#pragma unroll
            for (int m = 32; m >= 1; m >>= 1) e += __shfl_xor(e, m, 64);
            if ((k & 63) == 0) red_s[k >> 6] = e;
        }
        __syncthreads();                                   // B3 (hf_s ready)
    }

    // ---- Final deferred hebb update (step 255's delta) -------------------
    {
        float eta = tanhfast(((red_s[0] + red_s[1]) + (red_s[2] + red_s[3])) + bmod);
        float mj = fmaf(eta, wf, bf) * jreg;
        h2_t mj2;
        mj2.x = (_Float16)mj;
        mj2.y = mj2.x;
        const uint4* hfO4 = (const uint4*)hf_s[0];   // h_254 (TT even)
        HBV_CHUNK(0, 0, 1, 2, 3)
        HBV_CHUNK(1, 4, 5, 6, 7)
        HBV_CHUNK(2, 8, 9, 10, 11)
        HBV_CHUNK(3, 12, 13, 14, 15)
    }

    const size_t HS = (size_t)TT * BB * HH;
    if (r == 0 && rg == 0) {
        out[HS + (size_t)b * HH + k]           = hnreg;  // h_255
        out[HS + BB * HH + (size_t)b * HH + k] = creg;   // c_255
    }
    float* hbout = out + HS + 2 * BB * HH + (size_t)b * HH * HH;
    HBQ_FOREACH(HBQ_OUT)
}

// ---------------------------------------------------------------------------
extern "C" void kernel_launch(void* const* d_in, const int* in_sizes, int n_in,
                              void* d_out, int out_size, void* d_ws,
                              size_t ws_size, hipStream_t stream) {
    const float* x     = (const float*)d_in[0];
    const float* Wx    = (const float*)d_in[1];
    const float* bx    = (const float*)d_in[2];
    const float* Wh    = (const float*)d_in[3];
    const float* bh    = (const float*)d_in[4];
    const float* w_mod = (const float*)d_in[5];
    const float* b_mod = (const float*)d_in[6];
    const float* w_fan = (const float*)d_in[7];
    const float* b_fan = (const float*)d_in[8];
    const float* alpha = (const float*)d_in[9];
    float* out = (float*)d_out;

    float*    xf  = (float*)d_ws;                           // 32 MiB
    uint4*    Wd2 = (uint4*)((char*)d_ws + 33554432);       // 512 KiB
    unsigned* alP = (unsigned*)((char*)d_ws + 34078720);    // 128 KiB
    u64*      exD = (u64*)((char*)d_ws + 34209792);         // 2 MiB

    hipLaunchKernelGGL(prep_wd2, dim3(128), dim3(256), 0, stream, Wh, Wd2);
    hipLaunchKernelGGL(prep_alp, dim3(128), dim3(256), 0, stream, alpha, alP);
    hipLaunchKernelGGL(xf_gemm, dim3(16, 128), dim3(256), 0, stream,
                       x, Wx, bx, bh, xf);
    hipLaunchKernelGGL(scan_kernel, dim3(64), dim3(1024), 0, stream,
                       xf, Wd2, alP, w_mod, b_mod, w_fan, b_fan,
                       exD, out);
}

// Round 2
// 757.543 us; speedup vs baseline: 1.4360x; 1.4360x over previous
//
#include <hip/hip_runtime.h>

// PlasticLSTM: T=256, B=32, I=128, H=256, 4H=1024, CLIP=2
// d_out: hs[T,B,H] ++ h[B,H] ++ c[B,H] ++ hebb[B,H,H]  (fp32, concat flat)
//
// Round-12: revert to the proven round-10 structure (4-way split-K,
// 128 blocks, 48-VGPR per-thread state) and attack the exchange RT:
// partner blocks (bid, bid+32, +64, +96) are all congruent mod 8, so under
// the measured round-robin block->XCD mapping they share one XCD L2.
// DUAL-PUBLISH: plain store to a fast region (lands in the shared L2) +
// agent-scope tagged store to the safe region (coherence point), and
// HYBRID-POLL: 3 iterations of sc0 (L1-bypass, L2-hit) loads on the fast
// region, then 1 agent-scope iteration as correctness backstop. Exact-tag
// match makes stale fast lines harmless; if blocks land on different XCDs
// the safe path alone reproduces round-10 behavior (no hang possible).
// Also: xf prefetched one step ahead; phase 2 lightened for rg>0 waves
// (they only need jreg).

#define TT 256
#define BB 32
#define II 128
#define HH 256
#define G4 1024

typedef _Float16 h2_t __attribute__((ext_vector_type(2)));
typedef unsigned long long u64;

__device__ __forceinline__ float sigm(float x) {
    return 1.0f / (1.0f + __expf(-x));
}
__device__ __forceinline__ float tanhfast(float x) {
    return 1.0f - 2.0f / (__expf(2.0f * x) + 1.0f);
}
__device__ __forceinline__ unsigned pkh(float lo, float hi) {
    h2_t v;
    v.x = (_Float16)lo;
    v.y = (_Float16)hi;
    return __builtin_bit_cast(unsigned, v);
}

#if __has_builtin(__builtin_amdgcn_fdot2)
__device__ __forceinline__ float dot2(unsigned a, unsigned b, float c) {
    return __builtin_amdgcn_fdot2(__builtin_bit_cast(h2_t, a),
                                  __builtin_bit_cast(h2_t, b), c, false);
}
#else
__device__ __forceinline__ float dot2(unsigned a, unsigned b, float c) {
    h2_t av = __builtin_bit_cast(h2_t, a), bv = __builtin_bit_cast(h2_t, b);
    return c + (float)av.x * (float)bv.x + (float)av.y * (float)bv.y;
}
#endif

__device__ __forceinline__ h2_t pkfma(h2_t a, h2_t b, h2_t c) {
#if __has_builtin(__builtin_elementwise_fma)
    return __builtin_elementwise_fma(a, b, c);
#else
    return a * b + c;
#endif
}
__device__ __forceinline__ h2_t clip2h(h2_t x) {
    const h2_t lo = {(_Float16)-2.0f, (_Float16)-2.0f};
    const h2_t hi = {(_Float16)2.0f, (_Float16)2.0f};
#if __has_builtin(__builtin_elementwise_max) && __has_builtin(__builtin_elementwise_min)
    return __builtin_elementwise_min(__builtin_elementwise_max(x, lo), hi);
#else
    h2_t r = x;
    r.x = r.x < lo.x ? lo.x : (r.x > hi.x ? hi.x : r.x);
    r.y = r.y < lo.y ? lo.y : (r.y > hi.y ? hi.y : r.y);
    return r;
#endif
}

// Fast-path poll: 3 L1-bypass (sc0) 8-byte loads, serviced by the XCD's L2.
__device__ __forceinline__ void ld3_fast(const u64* p1, const u64* p2,
                                         const u64* p3,
                                         u64& v1, u64& v2, u64& v3) {
    asm volatile(
        "global_load_dwordx2 %0, %3, off sc0\n\t"
        "global_load_dwordx2 %1, %4, off sc0\n\t"
        "global_load_dwordx2 %2, %5, off sc0\n\t"
        "s_waitcnt vmcnt(0)"
        : "=&v"(v1), "=&v"(v2), "=&v"(v3)
        : "v"(p1), "v"(p2), "v"(p3));
}

// ---------------------------------------------------------------------------
// Wd3: idx = ro*4096 + g*4 + ri ; entry = 8 f16 of Wh[g][8*(4ro+ri) .. +7]
// ---------------------------------------------------------------------------
__global__ __launch_bounds__(256) void prep_wd3(const float* __restrict__ Wh,
                                                uint4* __restrict__ Wd3) {
    int idx = blockIdx.x * 256 + threadIdx.x;   // 32768
    int ro = idx >> 12, rem = idx & 4095;
    int g = rem >> 2, ri = rem & 3;
    int r8 = 4 * ro + ri;
    const float4* s = (const float4*)(Wh + (size_t)g * HH + (r8 << 3));
    float4 a = s[0], b2 = s[1];
    uint4 o;
    o.x = pkh(a.x, a.y);
    o.y = pkh(a.z, a.w);
    o.z = pkh(b2.x, b2.y);
    o.w = pkh(b2.z, b2.w);
    Wd3[idx] = o;
}

// ---------------------------------------------------------------------------
// alQ: idx = p4*256 + k -> uint4; comp j = f16 pair {alpha[2*(4p4+j)][k], +1}
// ---------------------------------------------------------------------------
__global__ __launch_bounds__(256) void prep_alq(const float* __restrict__ alpha,
                                                uint4* __restrict__ alQ) {
    int idx = blockIdx.x * 256 + threadIdx.x;   // 8192
    int p4 = idx >> 8, k = idx & 255;
    unsigned r[4];
#pragma unroll
    for (int j = 0; j < 4; ++j) {
        int p = 4 * p4 + j;
        float a0 = alpha[(size_t)(2 * p) * HH + k];
        float a1 = alpha[(size_t)(2 * p + 1) * HH + k];
        r[j] = pkh(a0, a1);
    }
    uint4 o; o.x = r[0]; o.y = r[1]; o.z = r[2]; o.w = r[3];
    alQ[idx] = o;
}

// ---------------------------------------------------------------------------
// xf[t,b,g] = sum_i x[t,b,i]*Wx[g,i] + bx[g] + bh[g]
// ---------------------------------------------------------------------------
__global__ __launch_bounds__(256) void xf_gemm(const float* __restrict__ x,
                                               const float* __restrict__ Wx,
                                               const float* __restrict__ bx,
                                               const float* __restrict__ bh,
                                               float* __restrict__ xf) {
    __shared__ float As[64][37];
    __shared__ float Bs[64][37];
    const int tid = threadIdx.x;
    const int tx = tid & 15, ty = tid >> 4;
    const int m0 = blockIdx.y << 6;
    const int n0 = blockIdx.x << 6;
    float c[4][4] = {};

    for (int k0 = 0; k0 < II; k0 += 32) {
#pragma unroll
        for (int hh = 0; hh < 2; ++hh) {
            int row = (tid >> 3) + (hh << 5);
            int col = (tid & 7) << 2;
            float4 va = *(const float4*)(x + (size_t)(m0 + row) * II + k0 + col);
            As[row][col] = va.x; As[row][col + 1] = va.y;
            As[row][col + 2] = va.z; As[row][col + 3] = va.w;
            float4 vb = *(const float4*)(Wx + (size_t)(n0 + row) * II + k0 + col);
            Bs[row][col] = vb.x; Bs[row][col + 1] = vb.y;
            Bs[row][col + 2] = vb.z; Bs[row][col + 3] = vb.w;
        }
        __syncthreads();
#pragma unroll
        for (int kk = 0; kk < 32; ++kk) {
            float a[4], bb[4];
#pragma unroll
            for (int u = 0; u < 4; ++u) a[u] = As[(ty << 2) + u][kk];
#pragma unroll
            for (int v = 0; v < 4; ++v) bb[v] = Bs[(tx << 2) + v][kk];
#pragma unroll
            for (int u = 0; u < 4; ++u)
#pragma unroll
                for (int v = 0; v < 4; ++v)
                    c[u][v] = fmaf(a[u], bb[v], c[u][v]);
        }
        __syncthreads();
    }
    const int n = n0 + (tx << 2);
    float4 bxv = *(const float4*)(bx + n);
    float4 bhv = *(const float4*)(bh + n);
    float4 badd = {bxv.x + bhv.x, bxv.y + bhv.y, bxv.z + bhv.z, bxv.w + bhv.w};
#pragma unroll
    for (int u = 0; u < 4; ++u) {
        int m = m0 + (ty << 2) + u;
        float4 o = {c[u][0] + badd.x, c[u][1] + badd.y,
                    c[u][2] + badd.z, c[u][3] + badd.w};
        *(float4*)(xf + (size_t)m * G4 + n) = o;
    }
}

// ---------------------------------------------------------------------------
// hebb: 8 NAMED half2 regs/thread (rows r0g+2i, r0g+2i+1; r0g = r*64+rg*16).
// ---------------------------------------------------------------------------
#define HBQ_FOREACH(X) X(0) X(1) X(2) X(3) X(4) X(5) X(6) X(7)

#define HBQ_DECL(i) h2_t hp##i = {(_Float16)0.0f, (_Float16)0.0f};
#define HBQ_OUT(i) \
    hbout[(size_t)(r0g + 2 * i) * HH + k]     = (float)hp##i.x; \
    hbout[(size_t)(r0g + 2 * i + 1) * HH + k] = (float)hp##i.y;

#define HBQ_STEP(i, au, hou, hnu) { \
    h2_t al2 = __builtin_bit_cast(h2_t, au); \
    h2_t ho2 = __builtin_bit_cast(h2_t, hou); \
    h2_t hn2 = __builtin_bit_cast(h2_t, hnu); \
    hp##i = clip2h(pkfma(mj2, ho2, hp##i)); \
    h2_t hna = hn2 * al2; \
    pp = dot2(__builtin_bit_cast(unsigned, hna), \
              __builtin_bit_cast(unsigned, hp##i), pp); }

#define HBQ_CHUNK(q, AV, i0, i1, i2, i3) { \
    uint4 ho = hfO4[hb4 + (q)]; \
    uint4 hn = hfN4[hb4 + (q)]; \
    HBQ_STEP(i0, AV.x, ho.x, hn.x) \
    HBQ_STEP(i1, AV.y, ho.y, hn.y) \
    HBQ_STEP(i2, AV.z, ho.z, hn.z) \
    HBQ_STEP(i3, AV.w, ho.w, hn.w) }

#define HBV_STEP(i, hou) { \
    h2_t ho2 = __builtin_bit_cast(h2_t, hou); \
    hp##i = clip2h(pkfma(mj2, ho2, hp##i)); }
#define HBV_CHUNK(q, i0, i1, i2, i3) { \
    uint4 ho = hfO4[hb4 + (q)]; \
    HBV_STEP(i0, ho.x) HBV_STEP(i1, ho.y) \
    HBV_STEP(i2, ho.z) HBV_STEP(i3, ho.w) }

#define DOTW(W, HV) { \
    ac0 = dot2(W.x, HV.x, ac0); ac1 = dot2(W.y, HV.y, ac1); \
    ac2 = dot2(W.z, HV.z, ac2); ac3 = dot2(W.w, HV.w, ac3); }

#define PUBLISH(val) { \
    u64 pkv = ((u64)tag << 32) | (u64)__builtin_bit_cast(unsigned, val); \
    __hip_atomic_store(&myF[off], pkv, __ATOMIC_RELAXED, \
                       __HIP_MEMORY_SCOPE_WORKGROUP); \
    __hip_atomic_store(&myEx[off], pkv, __ATOMIC_RELAXED, \
                       __HIP_MEMORY_SCOPE_AGENT); }

__global__ __launch_bounds__(1024, 1) void scan_kernel(
    const float* __restrict__ xf,      // [T,B,4H], biases folded
    const uint4* __restrict__ Wd3,
    const uint4* __restrict__ alQ,
    const float* __restrict__ w_mod,
    const float* __restrict__ b_mod,
    const float* __restrict__ w_fan,
    const float* __restrict__ b_fan,
    u64* __restrict__ exData,          // [32][4][2][1024] u64 {tag|f32} safe
    u64* __restrict__ exFast,          // same layout, XCD-L2 fast copies
    float* __restrict__ out) {
    const int bid = blockIdx.x;
    const int r   = bid >> 5;          // role 0..3: rows r*64..r*64+63
    const int b   = bid & 31;          // batch element
    const int tid = threadIdx.x;
    const int k   = tid & (HH - 1);
    const int rg  = tid >> 8;          // 0..3
    const int r0g = r * 64 + rg * 16;  // first hebb row owned
    const int hb4 = r0g >> 3;          // uint4 index of row r0g in hf_s

    __shared__ alignas(16) unsigned short hf_s[2][HH];
    __shared__ float fioj_s[G4];
    __shared__ float pp_s[4][HH];
    __shared__ float red_s[4];

    HBQ_FOREACH(HBQ_DECL)

    if (tid < HH) {
        hf_s[0][tid] = 0;
        hf_s[1][tid] = 0;
    }
    if (tid < 4) red_s[tid] = 0.0f;
    __syncthreads();

    const float bmod = b_mod[0];
    const float wf = w_fan[k], bf = b_fan[k], wm = w_mod[k];
    float creg = 0.0f, jreg = 0.0f, hnreg = 0.0f;

    // ---- Register-resident weights (rows r*64..+63 for column g=tid) -----
    const uint4* wb = Wd3 + ((size_t)(2 * r) << 12) + (tid << 2);
    uint4 w0 = wb[0], w1 = wb[1], w2 = wb[2], w3 = wb[3];
    uint4 w4 = wb[4096], w5 = wb[4097], w6 = wb[4098], w7 = wb[4099];
    // ---- Register-resident alpha (8 row-pairs for column k) --------------
    uint4 aqA = alQ[(size_t)(8 * r + 2 * rg) * 256 + k];
    uint4 aqB = alQ[(size_t)(8 * r + 2 * rg + 1) * 256 + k];

    const float* xfp = xf + (size_t)b * G4 + tid;
    float xcur = (rg == r) ? xfp[0] : 0.0f;   // step-0 xf, prefetched

    u64* myEx = exData + (size_t)((b * 4 + r) * 2) * 1024;
    const u64* pEx1 = exData + (size_t)((b * 4 + ((r + 1) & 3)) * 2) * 1024;
    const u64* pEx2 = exData + (size_t)((b * 4 + ((r + 2) & 3)) * 2) * 1024;
    const u64* pEx3 = exData + (size_t)((b * 4 + ((r + 3) & 3)) * 2) * 1024;
    u64* myF = exFast + (size_t)((b * 4 + r) * 2) * 1024;
    const u64* pF1 = exFast + (size_t)((b * 4 + ((r + 1) & 3)) * 2) * 1024;
    const u64* pF2 = exFast + (size_t)((b * 4 + ((r + 2) & 3)) * 2) * 1024;
    const u64* pF3 = exFast + (size_t)((b * 4 + ((r + 3) & 3)) * 2) * 1024;

    for (int t = 0; t < TT; ++t) {
        // prefetch next step's xf (latency hidden under this whole step)
        float xnext = 0.0f;
        if (rg == r && t + 1 < TT) xnext = xfp[(size_t)(t + 1) * BB * G4];

        const unsigned tag = (unsigned)(t + 1);
        const int off = (t & 1) * 1024 + tid;

        // ---- Phase 1a: eta_{t-1}; deferred hebb update + plast(t) fused ---
        float eta = tanhfast(((red_s[0] + red_s[1]) + (red_s[2] + red_s[3])) + bmod);
        float mj = fmaf(eta, wf, bf) * jreg;    // 0 at t=0
        h2_t mj2;
        mj2.x = (_Float16)mj;
        mj2.y = mj2.x;
        const uint4* hfO4 = (const uint4*)hf_s[t & 1];        // h_{t-2}
        const uint4* hfN4 = (const uint4*)hf_s[(t & 1) ^ 1];  // h_{t-1}
        float pp = 0.0f;
        HBQ_CHUNK(0, aqA, 0, 1, 2, 3)
        HBQ_CHUNK(1, aqB, 4, 5, 6, 7)
        pp_s[rg][k] = pp;

        // ---- Phase 1b: quarter-K gate matvec, weights in registers --------
        float ac0 = 0.f, ac1 = 0.f, ac2 = 0.f, ac3 = 0.f;
        {
            const int hx = r << 3;
            uint4 h0 = hfN4[hx], h1 = hfN4[hx + 1];
            uint4 h2 = hfN4[hx + 2], h3 = hfN4[hx + 3];
            DOTW(w0, h0) DOTW(w1, h1) DOTW(w2, h2) DOTW(w3, h3)
            uint4 h4 = hfN4[hx + 4], h5 = hfN4[hx + 5];
            uint4 h6 = hfN4[hx + 6], h7 = hfN4[hx + 7];
            DOTW(w4, h4) DOTW(w5, h5) DOTW(w6, h6) DOTW(w7, h7)
        }
        float part = ((ac0 + ac1) + (ac2 + ac3)) + xcur;
        xcur = xnext;

        // f/i/o partials are final: publish before B1 (starts the RT early)
        if (tid < 768) PUBLISH(part)
        __syncthreads();                                   // B1 (pp_s ready)

        // j-gate quarter folds own plast partials, then publishes
        if (tid >= 768) {
            int k2 = tid - 768;
            part += (pp_s[0][k2] + pp_s[1][k2]) + (pp_s[2][k2] + pp_s[3][k2]);
            PUBLISH(part)
        }

        // ---- hybrid poll: 3x fast (XCD L2) iterations, then 1x safe -------
        {
            float s1 = 0.f, s2 = 0.f, s3 = 0.f;
            bool d1 = false, d2 = false, d3 = false;
            const u64* f1 = pF1 + off;
            const u64* f2 = pF2 + off;
            const u64* f3 = pF3 + off;
            int it = 0;
            do {
                u64 v1, v2, v3;
                if ((it & 3) != 3) {
                    ld3_fast(f1, f2, f3, v1, v2, v3);
                } else {
                    v1 = __hip_atomic_load(pEx1 + off, __ATOMIC_RELAXED,
                                           __HIP_MEMORY_SCOPE_AGENT);
                    v2 = __hip_atomic_load(pEx2 + off, __ATOMIC_RELAXED,
                                           __HIP_MEMORY_SCOPE_AGENT);
                    v3 = __hip_atomic_load(pEx3 + off, __ATOMIC_RELAXED,
                                           __HIP_MEMORY_SCOPE_AGENT);
                }
                ++it;
                if (!d1 && (unsigned)(v1 >> 32) == tag) {
                    s1 = __builtin_bit_cast(float, (unsigned)v1);
                    d1 = true;
                }
                if (!d2 && (unsigned)(v2 >> 32) == tag) {
                    s2 = __builtin_bit_cast(float, (unsigned)v2);
                    d2 = true;
                }
                if (!d3 && (unsigned)(v3 >> 32) == tag) {
                    s3 = __builtin_bit_cast(float, (unsigned)v3);
                    d3 = true;
                }
            } while (!(d1 && d2 && d3));
            fioj_s[tid] = part + ((s1 + s2) + s3);
        }
        __syncthreads();                                   // B2 (fioj ready)

        // ---- Phase 2: jreg for everyone; full cell update only on rg==0 ---
        jreg = tanhfast(fioj_s[3 * HH + k]);   // plast already folded in
        if (rg == 0) {   // waves 0-3, wave-uniform
            float fg = sigm(fioj_s[k]);
            float ig = sigm(fioj_s[HH + k]);
            float og = sigm(fioj_s[2 * HH + k]);
            creg = fmaf(fg, creg, ig * jreg);
            hnreg = og * tanhfast(creg);
            _Float16 hh = (_Float16)hnreg;
            hf_s[t & 1][k] = __builtin_bit_cast(unsigned short, hh);
            if (r == 0) out[((size_t)t * BB + b) * HH + k] = hnreg;
            float e = creg * wm;
#pragma unroll
            for (int m = 32; m >= 1; m >>= 1) e += __shfl_xor(e, m, 64);
            if ((k & 63) == 0) red_s[k >> 6] = e;
        }
        __syncthreads();                                   // B3 (hf_s ready)
    }

    // ---- Final deferred hebb update (step 255's delta) -------------------
    {
        float eta = tanhfast(((red_s[0] + red_s[1]) + (red_s[2] + red_s[3])) + bmod);
        float mj = fmaf(eta, wf, bf) * jreg;
        h2_t mj2;
        mj2.x = (_Float16)mj;
        mj2.y = mj2.x;
        const uint4* hfO4 = (const uint4*)hf_s[0];   // h_254 (TT even)
        HBV_CHUNK(0, 0, 1, 2, 3)
        HBV_CHUNK(1, 4, 5, 6, 7)
    }

    const size_t HS = (size_t)TT * BB * HH;
    if (r == 0 && rg == 0) {
        out[HS + (size_t)b * HH + k]           = hnreg;  // h_255
        out[HS + BB * HH + (size_t)b * HH + k] = creg;   // c_255
    }
    float* hbout = out + HS + 2 * BB * HH + (size_t)b * HH * HH;
    HBQ_FOREACH(HBQ_OUT)
}

// ---------------------------------------------------------------------------
extern "C" void kernel_launch(void* const* d_in, const int* in_sizes, int n_in,
                              void* d_out, int out_size, void* d_ws,
                              size_t ws_size, hipStream_t stream) {
    const float* x     = (const float*)d_in[0];
    const float* Wx    = (const float*)d_in[1];
    const float* bx    = (const float*)d_in[2];
    const float* Wh    = (const float*)d_in[3];
    const float* bh    = (const float*)d_in[4];
    const float* w_mod = (const float*)d_in[5];
    const float* b_mod = (const float*)d_in[6];
    const float* w_fan = (const float*)d_in[7];
    const float* b_fan = (const float*)d_in[8];
    const float* alpha = (const float*)d_in[9];
    float* out = (float*)d_out;

    float* xf  = (float*)d_ws;                              // 32 MiB
    uint4* Wd3 = (uint4*)((char*)d_ws + 33554432);          // 512 KiB
    uint4* alQ = (uint4*)((char*)d_ws + 34078720);          // 128 KiB
    u64*   exD = (u64*)((char*)d_ws + 34209792);            // 2 MiB safe
    u64*   exF = (u64*)((char*)d_ws + 36306944);            // 2 MiB fast

    hipLaunchKernelGGL(prep_wd3, dim3(128), dim3(256), 0, stream, Wh, Wd3);
    hipLaunchKernelGGL(prep_alq, dim3(32), dim3(256), 0, stream, alpha, alQ);
    hipLaunchKernelGGL(xf_gemm, dim3(16, 128), dim3(256), 0, stream,
                       x, Wx, bx, bh, xf);
    hipLaunchKernelGGL(scan_kernel, dim3(128), dim3(1024), 0, stream,
                       xf, Wd3, alQ, w_mod, b_mod, w_fan, b_fan,
                       exD, exF, out);
}